// Round 13
// baseline (3111.713 us; speedup 1.0000x reference)
//
#include <hip/hip_runtime.h>

// LSTM: H=1024, B=1024, S=128 (T=127 steps), E=6, V=3, C=10.
// All float tensors FP32; x int32; output FP32 (1024 x 10).
// R13: launch-overhead probe + lowest-W step kernel.
//  - 256 blocks (1/CU), 4 waves; wave tile 16 rows x 4 gates x 64 cols (nt=4)
//    -> per-CU ds issue (6.1k cyc) < MFMA pipe (9.9k cyc): MFMA-bound.
//  - ONE barrier/step: 64 KB LDS holds k<512 (all gates); k>=512 a-frags
//    streamed from L2 (frag-major, immediate offsets). b-ring never drained.
//  - If total stays ~2900 despite W~5us, fixed per-launch overhead F~15us is
//    proven and R14 targets launch count; if total drops to ~1.2-1.8ms, W-theory.
constexpr int kH = 1024;
constexpr int kB = 1024;
constexpr int kS = 128;
constexpr int kT = 127;
constexpr int kE = 6;
constexpr int kV = 3;
constexpr int kC = 10;

typedef short s16x8 __attribute__((ext_vector_type(8)));
typedef short s16x4 __attribute__((ext_vector_type(4)));
typedef float f32x4 __attribute__((ext_vector_type(4)));
typedef unsigned short u16;

__device__ __forceinline__ float b2f(u16 u) {
    return __uint_as_float(((unsigned)u) << 16);
}
__device__ __forceinline__ u16 f2b(float f) {
    unsigned u = __float_as_uint(f);
    return (u16)((u + 0x7FFFu + ((u >> 16) & 1u)) >> 16);   // RNE
}
__device__ __forceinline__ float sigmoid_fast(float x) {
    return 1.0f / (1.0f + __expf(-x));
}
__device__ __forceinline__ float tanh_fast(float x) {
    return 2.0f / (1.0f + __expf(-2.0f * x)) - 1.0f;
}
__device__ __forceinline__ float clamp30(float x) {
    return fminf(fmaxf(x, -30.0f), 30.0f);
}

__device__ __forceinline__ void async_copy16(const u16* g, u16* l) {
    __builtin_amdgcn_global_load_lds(
        (const __attribute__((address_space(1))) void*)g,
        (__attribute__((address_space(3))) void*)l, 16, 0, 0);
}

// ---------------------------------------------------------------------------
// Prep 1: weights fp32 -> bf16, frag-major (same layout as R12):
//   grp = (((by*4 + kc)*4 + g)*8 + k0w)*64 + lane
//   wsw[grp*8 + j] = W_g[by*16 + (lane&15)][kc*256 + k0w*32 + (lane>>4)*8 + j]
// Per-by slice = 65536 shorts (128 KB); kc in {0,1} = k<512 = first 64 KB.
// ---------------------------------------------------------------------------
__global__ __launch_bounds__(256) void prep_weights(
    const float* __restrict__ Wgh, const float* __restrict__ Wih,
    const float* __restrict__ Wfh, const float* __restrict__ Woh,
    u16* __restrict__ wsw)
{
    unsigned grp = blockIdx.x * 256 + threadIdx.x;    // 0 .. 2^19-1
    const int lane = grp & 63;
    const int lm   = lane & 15;
    const int quad = lane >> 4;
    const int k0   = (grp >> 6) & 7;
    const int g    = (grp >> 9) & 3;
    const int kc   = (grp >> 11) & 3;
    const int by   = grp >> 13;                       // 0..63
    const float* src = (g == 0) ? Wgh : (g == 1) ? Wih : (g == 2) ? Wfh : Woh;
    const int row = by * 16 + lm;
    const int k   = kc * 256 + k0 * 32 + quad * 8;
    f32x4 v0 = *(const f32x4*)(src + (size_t)row * kH + k);
    f32x4 v1 = *(const f32x4*)(src + (size_t)row * kH + k + 4);
    s16x8 o;
#pragma unroll
    for (int j = 0; j < 4; ++j) o[j] = (short)f2b(v0[j]);
#pragma unroll
    for (int j = 0; j < 4; ++j) o[4 + j] = (short)f2b(v1[j]);
    *(s16x8*)(wsw + (size_t)grp * 8) = o;
}

// ---------------------------------------------------------------------------
// Prep 2: transpose h0 (H,B) fp32 -> hA (B,H) bf16; c0 (H,B) -> cT (B,H) fp32.
// ---------------------------------------------------------------------------
__global__ __launch_bounds__(1024) void prep_hc(
    const float* __restrict__ h0, const float* __restrict__ c0,
    u16* __restrict__ hA, float* __restrict__ cT)
{
    __shared__ float th[32][33];
    __shared__ float tc[32][33];
    int b = blockIdx.x * 32 + threadIdx.x;
    int h = blockIdx.y * 32 + threadIdx.y;
    th[threadIdx.y][threadIdx.x] = h0[(size_t)h * kB + b];
    tc[threadIdx.y][threadIdx.x] = c0[(size_t)h * kB + b];
    __syncthreads();
    int ob = blockIdx.x * 32 + threadIdx.y;
    int oh = blockIdx.y * 32 + threadIdx.x;
    hA[(size_t)ob * kH + oh] = f2b(th[threadIdx.x][threadIdx.y]);
    cT[(size_t)ob * kH + oh] = tc[threadIdx.x][threadIdx.y];
}

// ---------------------------------------------------------------------------
// Prep 3: gate constants as f32x4 per (g, row4, vocab):
//   Qp[((g*256 + hr4)*4 + v)*4 + reg] = b_g[hr4*4+reg] + sum_e W_gx[.,e]*emb[v,e]
// ---------------------------------------------------------------------------
__global__ __launch_bounds__(256) void prep_q(
    const float* __restrict__ Wgx, const float* __restrict__ Wix,
    const float* __restrict__ Wfx, const float* __restrict__ Wox,
    const float* __restrict__ bg,  const float* __restrict__ bi,
    const float* __restrict__ bf_, const float* __restrict__ bo,
    const float* __restrict__ emb, float* __restrict__ Qp)
{
    int tid = blockIdx.x * blockDim.x + threadIdx.x;   // 0..4095
    if (tid >= 4096) return;
    int g   = tid >> 10;
    int hr4 = (tid & 1023) >> 2;
    int v   = tid & 3;
    const float* Wx = (g == 0) ? Wgx : (g == 1) ? Wix : (g == 2) ? Wfx : Wox;
    const float* bb = (g == 0) ? bg  : (g == 1) ? bi  : (g == 2) ? bf_ : bo;
    f32x4 o;
#pragma unroll
    for (int reg = 0; reg < 4; ++reg) {
        int row = hr4 * 4 + reg;
        float s = bb[row];
        if (v < kV) {
#pragma unroll
            for (int e = 0; e < kE; ++e) s += Wx[row * kE + e] * emb[v * kE + e];
        }
        o[reg] = s;
    }
    *(f32x4*)(Qp + (size_t)tid * 4) = o;
}

// ---------------------------------------------------------------------------
// One LSTM timestep. Grid 256 x 256 thr (1 block/CU, 4 waves).
// xcd=blk&7, s=blk>>3, by=xcd*8+(s&7), bx=s>>3 -> per-XCD: 1 MB weights +
// 2 MB h + 0.5 MB c in L2. Block: 16 rows x 4 gates x 256 cols; wave: 64 cols.
// k<512 from LDS (staged once, 1 barrier); k>=512 a-frags streamed from L2.
// ---------------------------------------------------------------------------
__global__ __launch_bounds__(256) void lstm_step(
    const u16* __restrict__ wsw, const float* __restrict__ Qp,
    const int* __restrict__ x, int t,
    const short* __restrict__ hin, u16* __restrict__ hout,
    float* __restrict__ cT)
{
    __shared__ u16 wl[32768];   // 64 KB: k<512, frag-major

    const int tid  = threadIdx.x;
    const int lane = tid & 63;
    const int wave = tid >> 6;
    const int lm   = lane & 15;
    const int quad = lane >> 4;
    const int blk  = blockIdx.x;
    const int xcd  = blk & 7;
    const int s    = blk >> 3;              // 0..31
    const int by   = xcd * 8 + (s & 7);     // 0..63
    const int bx   = s >> 3;                // 0..3
    const int r0 = by * 16;
    const int cw = bx * 256 + wave * 64;

    const u16* wswblk = wsw + (size_t)by * 65536;

    // ---- stage k<512 weights into LDS (16 KB per wave, async) ----
#pragma unroll
    for (int rr = 0; rr < 16; ++rr) {
        const int ub = wave * 8192 + rr * 512;   // shorts
        async_copy16(wswblk + ub + lane * 8, &wl[ub]);
    }

    // ---- hoisted per-step loads: x -> vv -> Qp vectors; c state ----
    int vv[4];
#pragma unroll
    for (int nt = 0; nt < 4; ++nt) {
        int v = x[(size_t)(cw + nt * 16 + lm) * kS + t];
        vv[nt] = (v < 0) ? 0 : (v > kV - 1) ? (kV - 1) : v;
    }
    f32x4 qv[4][4];
#pragma unroll
    for (int nt = 0; nt < 4; ++nt)
#pragma unroll
        for (int g = 0; g < 4; ++g)
            qv[nt][g] = *(const f32x4*)(Qp +
                (size_t)(((g * 256 + by * 4 + quad) * 4 + vv[nt]) * 4));
    f32x4 cold[4];
#pragma unroll
    for (int nt = 0; nt < 4; ++nt)
        cold[nt] = *(const f32x4*)(cT +
            (size_t)(cw + nt * 16 + lm) * kH + r0 + quad * 4);

    asm volatile("s_waitcnt vmcnt(0)" ::: "memory");
    __syncthreads();   // the ONLY barrier in this kernel

    // ---- rings ----
    const int koff = quad * 8;
    const short* hrow[4];
#pragma unroll
    for (int nt = 0; nt < 4; ++nt)
        hrow[nt] = hin + (size_t)(cw + nt * 16 + lm) * kH + koff;

    s16x8 ar[3][4];   // a ring, prefetch distance 2
    s16x8 br[4][4];   // b ring, prefetch distance 3

    auto loadA = [&](int k0, s16x8 d[4]) {
        if (k0 < 16) {
            const int base = ((k0 >> 3) * 4) * 4096 + (k0 & 7) * 512 + lane * 8;
#pragma unroll
            for (int g = 0; g < 4; ++g)
                d[g] = *(const s16x8*)&wl[base + g * 4096];
        } else {
            const u16* gb = wswblk + ((size_t)(k0 >> 3) * 4) * 4096 +
                            (size_t)(k0 & 7) * 512 + lane * 8;
#pragma unroll
            for (int g = 0; g < 4; ++g)
                d[g] = *(const s16x8*)(gb + g * 4096);
        }
    };
    auto loadB = [&](int k0, s16x8 d[4]) {
#pragma unroll
        for (int nt = 0; nt < 4; ++nt)
            d[nt] = *(const s16x8*)(hrow[nt] + k0 * 32);
    };

    loadA(0, ar[0]); loadA(1, ar[1]);
    loadB(0, br[0]); loadB(1, br[1]); loadB(2, br[2]);

    f32x4 acc[4][4];
    const f32x4 zero = {0.f, 0.f, 0.f, 0.f};
#pragma unroll
    for (int g = 0; g < 4; ++g)
#pragma unroll
        for (int nt = 0; nt < 4; ++nt) acc[g][nt] = zero;

#pragma unroll
    for (int k0 = 0; k0 < 32; ++k0) {
        if (k0 + 2 < 32) loadA(k0 + 2, ar[(k0 + 2) % 3]);
        if (k0 + 3 < 32) loadB(k0 + 3, br[(k0 + 3) & 3]);
        const s16x8* a = ar[k0 % 3];
        const s16x8* b = br[k0 & 3];
#pragma unroll
        for (int g = 0; g < 4; ++g)
#pragma unroll
            for (int nt = 0; nt < 4; ++nt)
                acc[g][nt] = __builtin_amdgcn_mfma_f32_16x16x32_bf16(
                    a[g], b[nt], acc[g][nt], 0, 0, 0);
    }

    // ---- epilogue: pure ALU + stores. C/D: col=lane&15, row=quad*4+reg ----
#pragma unroll
    for (int nt = 0; nt < 4; ++nt) {
        const int c = cw + nt * 16 + lm;
        const int rb = r0 + quad * 4;
        f32x4 cnew;
        s16x4 hnew;
#pragma unroll
        for (int reg = 0; reg < 4; ++reg) {
            float pg = clamp30(acc[0][nt][reg] + qv[nt][0][reg]);
            float pi = clamp30(acc[1][nt][reg] + qv[nt][1][reg]);
            float pf = clamp30(acc[2][nt][reg] + qv[nt][2][reg]);
            float po = clamp30(acc[3][nt][reg] + qv[nt][3][reg]);
            float gg = tanh_fast(pg);
            float ii = sigmoid_fast(pi);
            float ff = sigmoid_fast(pf);
            float oo = sigmoid_fast(po);
            float c2 = gg * ii + cold[nt][reg] * ff;
            c2 = fminf(fmaxf(c2, -200.0f), 200.0f);
            cnew[reg] = c2;
            hnew[reg] = (short)f2b(tanh_fast(c2) * oo);
        }
        *(f32x4*)(cT + (size_t)c * kH + rb) = cnew;
        *(s16x4*)(hout + (size_t)c * kH + rb) = hnew;
    }
}

// ---------------------------------------------------------------------------
// Logits: p[b][cls] = h[b,:] . W_ph[cls,:] + b_p[cls]; log_softmax over 10.
// ---------------------------------------------------------------------------
__global__ __launch_bounds__(256) void logits_kernel(
    const u16* __restrict__ hT, const float* __restrict__ Wph,
    const float* __restrict__ bp, float* __restrict__ out)
{
    const int wave = threadIdx.x >> 6;
    const int lane = threadIdx.x & 63;
    const int b = blockIdx.x * 4 + wave;

    const u16* hp = hT + (size_t)b * kH + lane * 16;
    float hf[16];
#pragma unroll
    for (int j = 0; j < 16; ++j) hf[j] = b2f(hp[j]);

    float p[kC];
#pragma unroll
    for (int cls = 0; cls < kC; ++cls) {
        const float* wp = Wph + (size_t)cls * kH + lane * 16;
        float s = 0.f;
#pragma unroll
        for (int j = 0; j < 16; ++j) s += hf[j] * wp[j];
#pragma unroll
        for (int off = 1; off < 64; off <<= 1) s += __shfl_xor(s, off, 64);
        p[cls] = fminf(fmaxf(s + bp[cls], -1.0e4f), 1.0e4f);
    }

    float m = p[0];
#pragma unroll
    for (int cls = 1; cls < kC; ++cls) m = fmaxf(m, p[cls]);
    float se = 0.f;
#pragma unroll
    for (int cls = 0; cls < kC; ++cls) se += __expf(p[cls] - m);
    float l = m + __logf(se);

    if (lane < kC) {
        float myp = p[0];
#pragma unroll
        for (int cls = 1; cls < kC; ++cls)
            if (lane == cls) myp = p[cls];
        out[(size_t)b * kC + lane] = myp - l;
    }
}

// ---------------------------------------------------------------------------
extern "C" void kernel_launch(void* const* d_in, const int* in_sizes, int n_in,
                              void* d_out, int out_size, void* d_ws, size_t ws_size,
                              hipStream_t stream)
{
    const int*   x   = (const int*)  d_in[0];
    const float* emb = (const float*)d_in[1];
    const float* Wgx = (const float*)d_in[2];
    const float* Wgh = (const float*)d_in[3];
    const float* bg  = (const float*)d_in[4];
    const float* Wix = (const float*)d_in[5];
    const float* Wih = (const float*)d_in[6];
    const float* bi  = (const float*)d_in[7];
    const float* Wfx = (const float*)d_in[8];
    const float* Wfh = (const float*)d_in[9];
    const float* bf_ = (const float*)d_in[10];
    const float* Wox = (const float*)d_in[11];
    const float* Woh = (const float*)d_in[12];
    const float* bo  = (const float*)d_in[13];
    const float* Wph = (const float*)d_in[14];
    const float* bp  = (const float*)d_in[15];
    const float* h0  = (const float*)d_in[16];
    const float* c0  = (const float*)d_in[17];

    char* ws = (char*)d_ws;
    float* Qp  = (float*)ws;                              // 64 KB
    u16*   hA  = (u16*)(ws + (64 << 10));                 // 2 MB
    u16*   hB  = hA + (size_t)kB * kH;                    // 2 MB
    float* cT  = (float*)(hB + (size_t)kB * kH);          // 4 MB
    u16*   wsw = (u16*)(cT + (size_t)kB * kH);            // 8 MB  (total ~16.1 MB)

    prep_weights<<<dim3(2048), dim3(256), 0, stream>>>(Wgh, Wih, Wfh, Woh, wsw);
    prep_hc<<<dim3(kB / 32, kH / 32), dim3(32, 32), 0, stream>>>(h0, c0, hA, cT);
    prep_q<<<dim3(16), dim3(256), 0, stream>>>(Wgx, Wix, Wfx, Wox, bg, bi, bf_, bo, emb, Qp);

    for (int t = 0; t < kT; ++t) {
        const u16* hin  = (t & 1) ? hB : hA;
        u16*       hout = (t & 1) ? hA : hB;
        lstm_step<<<dim3(256), dim3(256), 0, stream>>>(
            wsw, Qp, x, t, (const short*)hin, hout, cT);
    }
    // 127 steps: t=126 (even) wrote hB.
    logits_kernel<<<dim3(kB / 4), dim3(256), 0, stream>>>(hB, Wph, bp, (float*)d_out);
}